// Round 9
// baseline (473.817 us; speedup 1.0000x reference)
//
#include <hip/hip_runtime.h>

// VectorQuantizer: M=32768 rows, N=8192 codes, D=256, fp32.
// Outputs flat fp32: [z_out 8388608][loss 1][idx 32768]
// idx = argmax zf.cb (l2-normalized); z_out = cb[idx]; loss = 1.25*mean((cb[idx]-zf)^2)
//
// R16: revert R15's cooperative mega-kernel (idx corruption, unexplained).
// Base = R12 (232us, passing). Changes: (a) rescore launch-bounds cap REMOVED
// -- R11's (256,4) forced the 128-VGPR occupancy step while the fp64 tie path
// needs more -> suspected common-path scratch spills (R8 failure mode,
// invisible: rescore never makes top-5). Explains R11 neutrality (bound hurt
// canceled ns==1 gain). (b) loss folded into rescore via the R12-proven
// last-block atomic-counter reduction (partial[8192]; counter zeroed by
// normalize) -- kills the 4th dispatch + one gap. Scan/normalize byte-equal
// to R12 (scan 123us: quad-buffer global_load_lds, counted vmcnt(8)).

#define M_ROWS 32768
#define N_CODES 8192
#define DIM 256
#define NT 64             // 32-code tiles per quarter (2048 codes)
#define BUF_B 16384       // 32 code rows * 512B

typedef _Float16 v8h __attribute__((ext_vector_type(8)));
typedef float v4f __attribute__((ext_vector_type(4)));
typedef unsigned int uint;
typedef unsigned long long ull;

__device__ __forceinline__ unsigned short f2h(float f) {
    union { _Float16 h; unsigned short u; } c;
    c.h = (_Float16)f;                       // v_cvt_f16_f32, RTNE
    return c.u;
}
__device__ __forceinline__ uint umax2(uint a, uint b) { return a > b ? a : b; }
__device__ __forceinline__ uint umax3(uint a, uint b, uint c) {
    uint d; asm("v_max3_u32 %0, %1, %2, %3" : "=v"(d) : "v"(a), "v"(b), "v"(c)); return d;
}
__device__ __forceinline__ uint umed3(uint a, uint b, uint c) {
    uint d; asm("v_med3_u32 %0, %1, %2, %3" : "=v"(d) : "v"(a), "v"(b), "v"(c)); return d;
}
__device__ __forceinline__ int swz(int u, int r) {    // 16B-unit XOR swizzle (involution)
    return (u & 24) | ((u ^ r) & 7);
}
__device__ __forceinline__ void dma16(const void* g, void* l) {
    __builtin_amdgcn_global_load_lds(
        (const __attribute__((address_space(1))) unsigned int*)g,
        (__attribute__((address_space(3))) unsigned int*)l, 16, 0, 0);
}

// One wave per row; fused: blocks [0, N_CODES/4) normalize the codebook
// (fp32 out + PRE-SWIZZLED fp16 image for scan's global_load_lds), the rest
// normalize x rows (linear fp16). Swizzled image layout:
//   byte = r*512 + swz(lane>>1, r&31)*16 + (lane&1)*8
// Also zeroes the rescore last-block counter for this iteration.
__global__ __launch_bounds__(256) void normalize_kernel(
        const float* __restrict__ emb, const float* __restrict__ x,
        float* __restrict__ cb, unsigned short* __restrict__ cbh,
        unsigned short* __restrict__ zfh, uint* __restrict__ count) {
    if (blockIdx.x == 0 && threadIdx.x == 0) *count = 0u;
    int wave = threadIdx.x >> 6, lane = threadIdx.x & 63;
    int rg = blockIdx.x * 4 + wave;
    bool is_cb = rg < N_CODES;
    int r = is_cb ? rg : rg - N_CODES;
    const float* src = is_cb ? emb : x;
    float4 v = *(const float4*)(src + (size_t)r * DIM + lane * 4);
    float ss = v.x * v.x + v.y * v.y + v.z * v.z + v.w * v.w;
    #pragma unroll
    for (int o = 32; o; o >>= 1) ss += __shfl_xor(ss, o);
    float rinv = 1.0f / fmaxf(sqrtf(ss), 1e-12f);
    float4 o4; o4.x = v.x * rinv; o4.y = v.y * rinv; o4.z = v.z * rinv; o4.w = v.w * rinv;
    ushort4 b; b.x = f2h(o4.x); b.y = f2h(o4.y); b.z = f2h(o4.z); b.w = f2h(o4.w);
    if (is_cb) {
        *(float4*)(cb + (size_t)r * DIM + lane * 4) = o4;
        int rr = r & 31;
        size_t off = (size_t)r * 512
                   + (size_t)swz(lane >> 1, rr) * 16
                   + (size_t)(lane & 1) * 8;
        *(ushort4*)((char*)cbh + off) = b;
    } else {
        *(ushort4*)(zfh + (size_t)r * DIM + lane * 4) = b;
    }
}

// Scan (R12, byte-equal): block = 256 rows x one quarter (2048 codes). Wave w
// owns rows [w*64, w*64+64) as 4 MFMA row-groups sharing each B fragment.
// 32-code tiles: 16 ds_read_b128 -> 64 MFMA per tile per wave. Staging:
// global_load_lds width=16 from pre-swizzled cbh into linear quad-buffer.
// One raw s_barrier per tile; counted vmcnt(8) keeps 2 tiles of DMA in flight.
// Race-freedom: issue(t+3) into buf[(t+3)&3]=buf[(t-1)&3] happens after
// barrier(t), which implies ALL waves finished compute(t-1) on that buffer.
// Top-2 keys per (row, residue16): key = fp32bits(score+2) & ~0x1FF | tile9.
__global__ __launch_bounds__(256, 2) void scan_kernel(
        const unsigned short* __restrict__ zfh,
        const unsigned short* __restrict__ cbh,
        uint* __restrict__ cand) {   // [row][128] = [row][4quarter][16res][2]
    __shared__ __align__(16) char lds[4 * BUF_B];
    int tid = threadIdx.x, w = tid >> 6, lane = tid & 63;
    int m = lane & 15, g = lane >> 4;
    int rb = blockIdx.x >> 2, quarter = blockIdx.x & 3;
    int r0 = rb * 256 + w * 64;
    const v4f C2 = {2.f, 2.f, 2.f, 2.f};

    v8h a[4][8];
    #pragma unroll
    for (int h = 0; h < 4; ++h) {
        const unsigned short* ap = zfh + (size_t)(r0 + h * 16 + m) * DIM + g * 8;
        #pragma unroll
        for (int c = 0; c < 8; ++c) a[h][c] = *(const v8h*)(ap + c * 32);
    }
    asm volatile("" ::: "memory");   // pin a-loads before DMA issue order

    const char* cb_base = (const char*)cbh + ((size_t)quarter << 20);
    int wq = 4 * w;

    int roff[8];
    #pragma unroll
    for (int c = 0; c < 8; ++c)
        roff[c] = m * 512 + swz(4 * c + g, m) * 16;

    #pragma unroll
    for (int tt = 0; tt < 3; ++tt) {
        const char* gsrc = cb_base + (size_t)tt * BUF_B + wq * 1024 + lane * 16;
        char* lb = lds + (tt & 3) * BUF_B + wq * 1024;
        #pragma unroll
        for (int i = 0; i < 4; ++i) dma16(gsrc + i * 1024, lb + i * 1024);
    }

    uint top1[16], top2[16];
    #pragma unroll
    for (int i = 0; i < 16; ++i) { top1[i] = 0u; top2[i] = 0u; }

    for (int t = 0; t < NT; ++t) {
        if (t < NT - 2) asm volatile("s_waitcnt vmcnt(8)" ::: "memory");
        else            asm volatile("s_waitcnt vmcnt(0)" ::: "memory");
        __builtin_amdgcn_s_barrier();    // all waves' tile-t chunks visible
        if (t + 3 < NT) {
            const char* gsrc = cb_base + (size_t)(t + 3) * BUF_B + wq * 1024 + lane * 16;
            char* lb = lds + ((t + 3) & 3) * BUF_B + wq * 1024;
            #pragma unroll
            for (int i = 0; i < 4; ++i) dma16(gsrc + i * 1024, lb + i * 1024);
        }
        const char* cbuf = lds + (t & 3) * BUF_B;
        v4f acc[2][4];
        __builtin_amdgcn_s_setprio(1);
        #pragma unroll
        for (int s2 = 0; s2 < 2; ++s2) {
            #pragma unroll
            for (int c = 0; c < 8; ++c) {
                v8h b = *(const v8h*)(cbuf + s2 * 8192 + roff[c]);
                #pragma unroll
                for (int h = 0; h < 4; ++h) {
                    v4f cin = (c == 0) ? C2 : acc[s2][h];   // C=const: no init movs
                    acc[s2][h] = __builtin_amdgcn_mfma_f32_16x16x32_f16(a[h][c], b, cin, 0, 0, 0);
                }
            }
        }
        __builtin_amdgcn_s_setprio(0);
        uint gt0 = (uint)(quarter * 128 + 2 * t);
        uint gt1 = gt0 + 1u;
        #pragma unroll
        for (int i = 0; i < 16; ++i) {
            float s0 = acc[0][i >> 2][i & 3];           // in [1,3]: bits sortable
            float s1 = acc[1][i >> 2][i & 3];
            uint k0 = (__float_as_uint(s0) & 0xFFFFFE00u) | gt0;
            uint k1 = (__float_as_uint(s1) & 0xFFFFFE00u) | gt1;
            uint old1 = top1[i];
            top1[i] = umax3(old1, k0, k1);
            top2[i] = umax2(top2[i], umed3(old1, k0, k1));
        }
    }

    #pragma unroll
    for (int i = 0; i < 16; ++i) {
        int h = i >> 2, q = i & 3;
        int row = r0 + h * 16 + g * 4 + q;
        uint2 v2; v2.x = top1[i]; v2.y = top2[i];
        *(uint2*)(cand + (size_t)row * 128 + (quarter * 16 + m) * 2) = v2;
    }
}

// One wave per row. Prune 128 candidates at margin 0.008 (worst-case fp16 key
// skew ~0.0032), compact survivors via ballot-prefix into wave-private LDS.
// Speculative prefetch: the argmax-key lane's code is known right after the
// kmax reduce; ns==1 => spec IS the exact argmin. NO launch-bounds cap (the
// fp64 tie path was suspected of spilling under R11's (256,4)). Loss folded
// in: per-block partial + last-block (atomic counter) final reduce.
__global__ __launch_bounds__(256) void rescore_kernel(
        const float* __restrict__ x, const float* __restrict__ cb,
        const uint* __restrict__ cand, float* __restrict__ out,
        float* __restrict__ out_idx, float* __restrict__ loss_out,
        double* __restrict__ partial, uint* __restrict__ count) {
    __shared__ int s_surv[4][128];
    __shared__ double dsm[4];
    __shared__ int is_last;
    int w = threadIdx.x >> 6, lane = threadIdx.x & 63;
    int r = blockIdx.x * 4 + w;
    // Issue both independent HBM loads back-to-back before any reduction.
    float4 xv = *(const float4*)(x + (size_t)r * DIM + lane * 4);
    uint2 kk = *(const uint2*)(cand + (size_t)r * 128 + lane * 2);

    float ss = xv.x * xv.x + xv.y * xv.y + xv.z * xv.z + xv.w * xv.w;
    #pragma unroll
    for (int o = 32; o; o >>= 1) ss += __shfl_xor(ss, o);
    float rinv = 1.0f / fmaxf(sqrtf(ss), 1e-12f);
    float4 z4; z4.x = xv.x * rinv; z4.y = xv.y * rinv; z4.z = xv.z * rinv; z4.w = xv.w * rinv;

    float kf0 = __uint_as_float(kk.x & 0xFFFFFE00u);
    float kf1 = __uint_as_float(kk.y & 0xFFFFFE00u);
    int code0 = (int)(kk.x & 0x1FFu) * 16 + (lane & 15);
    int code1 = (int)(kk.y & 0x1FFu) * 16 + (lane & 15);
    float mykey = fmaxf(kf0, kf1);
    int mycode = (kf0 >= kf1) ? code0 : code1;
    float kmax = mykey;
    #pragma unroll
    for (int o = 32; o; o >>= 1) kmax = fmaxf(kmax, __shfl_xor(kmax, o));
    // Speculative winner: first lane holding the max key. Unique when ns==1.
    ull mm = __ballot(mykey == kmax);
    int spec = __shfl(mycode, (int)__builtin_ctzll(mm));
    float4 cspec = *(const float4*)(cb + (size_t)spec * DIM + lane * 4);

    float thr = kmax - 0.008f;
    bool p0 = kf0 >= thr, p1 = kf1 >= thr;
    ull m0 = __ballot(p0), m1 = __ballot(p1);
    ull lt = (1ull << lane) - 1ull;
    int ns0 = __popcll(m0);
    int ns = ns0 + __popcll(m1);
    if (p0) s_surv[w][__popcll(m0 & lt)] = code0;
    if (p1) s_surv[w][ns0 + __popcll(m1 & lt)] = code1;
    // wave-private LDS: same-wave DS ops execute in order; no barrier needed.

    int bestj;
    if (ns == 1) {
        // Unique within-margin survivor = the kmax key's owner = spec.
        // Margin covers worst-case fp16 skew => every possible winner
        // survives; ties are never pruned. Exact.
        bestj = spec;
    } else {
        float d1 = 3.0e38f; int jj = 0x7fffffff;
        int nsl = ns < 64 ? ns : 64;
        for (int s = 0; s < nsl; ++s) {
            int j = s_surv[w][s];
            float4 c4 = *(const float4*)(cb + (size_t)j * DIM + lane * 4);
            float d = c4.x * (c4.x - 2.f * z4.x) + c4.y * (c4.y - 2.f * z4.y)
                    + c4.z * (c4.z - 2.f * z4.z) + c4.w * (c4.w - 2.f * z4.w);
            #pragma unroll
            for (int o = 32; o; o >>= 1) d += __shfl_xor(d, o);
            if (lane == s) { d1 = d; jj = j; }
        }
        if (ns > 64) {   // effectively never for this data; correctness fallback
            float d2 = 3.0e38f; int jj2 = 0x7fffffff;
            for (int s = 64; s < ns; ++s) {
                int j = s_surv[w][s];
                float4 c4 = *(const float4*)(cb + (size_t)j * DIM + lane * 4);
                float d = c4.x * (c4.x - 2.f * z4.x) + c4.y * (c4.y - 2.f * z4.y)
                        + c4.z * (c4.z - 2.f * z4.z) + c4.w * (c4.w - 2.f * z4.w);
                #pragma unroll
                for (int o = 32; o; o >>= 1) d += __shfl_xor(d, o);
                if (lane == s - 64) { d2 = d; jj2 = j; }
            }
            if (d2 < d1 || (d2 == d1 && jj2 < jj)) { d1 = d2; jj = jj2; }
        }
        float dmin = d1;
        #pragma unroll
        for (int o = 32; o; o >>= 1) dmin = fminf(dmin, __shfl_xor(dmin, o));
        ull nearm = __ballot(d1 <= dmin + 2e-4f);
        if (__popcll(nearm) == 1) {
            bestj = __shfl(jj, (int)__builtin_ctzll(nearm));   // provably exact
        } else {
            double bestd = 1e300; bestj = 0x7fffffff;
            while (nearm) {
                int b = (int)__builtin_ctzll(nearm); nearm &= nearm - 1;
                int jc = __shfl(jj, b);
                float4 c4 = *(const float4*)(cb + (size_t)jc * DIM + lane * 4);
                double p = (double)c4.x * ((double)c4.x - 2.0 * (double)z4.x)
                         + (double)c4.y * ((double)c4.y - 2.0 * (double)z4.y)
                         + (double)c4.z * ((double)c4.z - 2.0 * (double)z4.z)
                         + (double)c4.w * ((double)c4.w - 2.0 * (double)z4.w);
                #pragma unroll
                for (int o = 32; o; o >>= 1) p += __shfl_xor(p, o);
                if (p < bestd || (p == bestd && jc < bestj)) { bestd = p; bestj = jc; }
            }
        }
    }
    float4 c4;
    if (bestj == spec) c4 = cspec;    // common path: already in registers
    else c4 = *(const float4*)(cb + (size_t)bestj * DIM + lane * 4);
    *(float4*)(out + (size_t)r * DIM + lane * 4) = c4;
    double dx = (double)c4.x - (double)z4.x, dy = (double)c4.y - (double)z4.y;
    double dz = (double)c4.z - (double)z4.z, dw = (double)c4.w - (double)z4.w;
    double lp = dx * dx + dy * dy + dz * dz + dw * dw;
    #pragma unroll
    for (int o = 32; o; o >>= 1) lp += __shfl_xor(lp, o);
    if (lane == 0) out_idx[r] = (float)bestj;

    // ---- loss: per-block partial, last-finishing block reduces all 8192 ----
    if (lane == 0) dsm[w] = lp;
    __syncthreads();
    if (threadIdx.x == 0) {
        partial[blockIdx.x] = dsm[0] + dsm[1] + dsm[2] + dsm[3];
        __threadfence();                       // partial visible before count
        uint old = atomicAdd(count, 1u);       // device-scope
        is_last = (old == (uint)(M_ROWS / 4 - 1));
    }
    __syncthreads();
    if (is_last) {
        __threadfence();                       // acquire all partials
        double s0 = 0.0, s1 = 0.0, s2 = 0.0, s3 = 0.0;
        for (int i = threadIdx.x; i < M_ROWS / 4; i += 1024) {
            s0 += partial[i];
            s1 += partial[i + 256];
            s2 += partial[i + 512];
            s3 += partial[i + 768];
        }
        double s = (s0 + s1) + (s2 + s3);
        #pragma unroll
        for (int o = 32; o; o >>= 1) s += __shfl_xor(s, o);
        __shared__ double fsm[4];
        if (lane == 0) fsm[w] = s;
        __syncthreads();
        if (threadIdx.x == 0)
            loss_out[0] = (float)(((fsm[0] + fsm[1]) + (fsm[2] + fsm[3])) *
                                  (1.25 / (double)(M_ROWS * DIM)));  // (BETA+1)*mean
    }
}

extern "C" void kernel_launch(void* const* d_in, const int* in_sizes, int n_in,
                              void* d_out, int out_size, void* d_ws, size_t ws_size,
                              hipStream_t stream) {
    const float* x   = (const float*)d_in[0];   // 32*1024*256
    const float* emb = (const float*)d_in[1];   // 8192*256
    float* out = (float*)d_out;
    char* ws = (char*)d_ws;

    float*          cb      = (float*)(ws);                          // 8 MB
    unsigned short* cbh     = (unsigned short*)(ws + (8u  << 20));   // 4 MB (swizzled fp16 image)
    unsigned short* zfh     = (unsigned short*)(ws + (12u << 20));   // 16 MB
    uint*           cand    = (uint*)(ws + (28u << 20));             // 16 MB
    double*         partial = (double*)(ws + (44u << 20));           // 64 KB
    uint*           count   = (uint*)(ws + (44u << 20) + (128u << 10)); // 4 B

    normalize_kernel<<<(N_CODES + M_ROWS) / 4, 256, 0, stream>>>(emb, x, cb, cbh, zfh, count);
    scan_kernel<<<512, 256, 0, stream>>>(zfh, cbh, cand);
    rescore_kernel<<<M_ROWS / 4, 256, 0, stream>>>(x, cb, cand,
                                                   out,
                                                   out + ((size_t)M_ROWS * DIM + 1),
                                                   out + (size_t)M_ROWS * DIM,
                                                   partial, count);
}

// Round 10
// 300.107 us; speedup vs baseline: 1.5788x; 1.5788x over previous
//
#include <hip/hip_runtime.h>

// VectorQuantizer: M=32768 rows, N=8192 codes, D=256, fp32.
// Outputs flat fp32: [z_out 8388608][loss 1][idx 32768]
// idx = argmax zf.cb (l2-normalized); z_out = cb[idx]; loss = 1.25*mean((cb[idx]-zf)^2)
//
// R17: R16's fold kept (3 dispatches) but the per-block __threadfence() is
// GONE -- on gfx940+ an agent-scope release fence emits an L2 writeback
// (per-XCD L2s non-coherent), and 8192 serialized writebacks were R16's
// 265us stall (rescore 275us @ VALUBusy 3.7%). Fence-free protocol: loss
// partial-sums via relaxed device-scope f64 atomicAdd into 64 slots (atomics
// execute at the device coherence point, no cache maintenance); an asm data
// dependency on the returned value orders loss-add before count-add, so
// count==8192 => all adds landed; last block reads slots with atomicAdd(+0.0).
// Rescore stays decapped (R16 measured VGPR=28 -- the R11 cap never bound).
// Scan/normalize byte-equal to R12 (scan 123us: quad-buffer global_load_lds,
// counted vmcnt(8), never drained in steady state).

#define M_ROWS 32768
#define N_CODES 8192
#define DIM 256
#define NT 64             // 32-code tiles per quarter (2048 codes)
#define BUF_B 16384       // 32 code rows * 512B

typedef _Float16 v8h __attribute__((ext_vector_type(8)));
typedef float v4f __attribute__((ext_vector_type(4)));
typedef unsigned int uint;
typedef unsigned long long ull;

__device__ __forceinline__ unsigned short f2h(float f) {
    union { _Float16 h; unsigned short u; } c;
    c.h = (_Float16)f;                       // v_cvt_f16_f32, RTNE
    return c.u;
}
__device__ __forceinline__ uint umax2(uint a, uint b) { return a > b ? a : b; }
__device__ __forceinline__ uint umax3(uint a, uint b, uint c) {
    uint d; asm("v_max3_u32 %0, %1, %2, %3" : "=v"(d) : "v"(a), "v"(b), "v"(c)); return d;
}
__device__ __forceinline__ uint umed3(uint a, uint b, uint c) {
    uint d; asm("v_med3_u32 %0, %1, %2, %3" : "=v"(d) : "v"(a), "v"(b), "v"(c)); return d;
}
__device__ __forceinline__ int swz(int u, int r) {    // 16B-unit XOR swizzle (involution)
    return (u & 24) | ((u ^ r) & 7);
}
__device__ __forceinline__ void dma16(const void* g, void* l) {
    __builtin_amdgcn_global_load_lds(
        (const __attribute__((address_space(1))) unsigned int*)g,
        (__attribute__((address_space(3))) unsigned int*)l, 16, 0, 0);
}

// One wave per row; fused: blocks [0, N_CODES/4) normalize the codebook
// (fp32 out + PRE-SWIZZLED fp16 image for scan's global_load_lds), the rest
// normalize x rows (linear fp16). Swizzled image layout:
//   byte = r*512 + swz(lane>>1, r&31)*16 + (lane&1)*8
// Block 0 also zeroes the rescore loss slots + counter for this iteration
// (visible to rescore via same-stream kernel-boundary ordering).
__global__ __launch_bounds__(256) void normalize_kernel(
        const float* __restrict__ emb, const float* __restrict__ x,
        float* __restrict__ cb, unsigned short* __restrict__ cbh,
        unsigned short* __restrict__ zfh, double* __restrict__ partial,
        uint* __restrict__ count) {
    if (blockIdx.x == 0) {
        if (threadIdx.x < 64) partial[threadIdx.x] = 0.0;
        else if (threadIdx.x == 64) *count = 0u;
    }
    int wave = threadIdx.x >> 6, lane = threadIdx.x & 63;
    int rg = blockIdx.x * 4 + wave;
    bool is_cb = rg < N_CODES;
    int r = is_cb ? rg : rg - N_CODES;
    const float* src = is_cb ? emb : x;
    float4 v = *(const float4*)(src + (size_t)r * DIM + lane * 4);
    float ss = v.x * v.x + v.y * v.y + v.z * v.z + v.w * v.w;
    #pragma unroll
    for (int o = 32; o; o >>= 1) ss += __shfl_xor(ss, o);
    float rinv = 1.0f / fmaxf(sqrtf(ss), 1e-12f);
    float4 o4; o4.x = v.x * rinv; o4.y = v.y * rinv; o4.z = v.z * rinv; o4.w = v.w * rinv;
    ushort4 b; b.x = f2h(o4.x); b.y = f2h(o4.y); b.z = f2h(o4.z); b.w = f2h(o4.w);
    if (is_cb) {
        *(float4*)(cb + (size_t)r * DIM + lane * 4) = o4;
        int rr = r & 31;
        size_t off = (size_t)r * 512
                   + (size_t)swz(lane >> 1, rr) * 16
                   + (size_t)(lane & 1) * 8;
        *(ushort4*)((char*)cbh + off) = b;
    } else {
        *(ushort4*)(zfh + (size_t)r * DIM + lane * 4) = b;
    }
}

// Scan (R12, byte-equal): block = 256 rows x one quarter (2048 codes). Wave w
// owns rows [w*64, w*64+64) as 4 MFMA row-groups sharing each B fragment.
// 32-code tiles: 16 ds_read_b128 -> 64 MFMA per tile per wave. Staging:
// global_load_lds width=16 from pre-swizzled cbh into linear quad-buffer.
// One raw s_barrier per tile; counted vmcnt(8) keeps 2 tiles of DMA in flight.
// Race-freedom: issue(t+3) into buf[(t+3)&3]=buf[(t-1)&3] happens after
// barrier(t), which implies ALL waves finished compute(t-1) on that buffer.
// Top-2 keys per (row, residue16): key = fp32bits(score+2) & ~0x1FF | tile9.
__global__ __launch_bounds__(256, 2) void scan_kernel(
        const unsigned short* __restrict__ zfh,
        const unsigned short* __restrict__ cbh,
        uint* __restrict__ cand) {   // [row][128] = [row][4quarter][16res][2]
    __shared__ __align__(16) char lds[4 * BUF_B];
    int tid = threadIdx.x, w = tid >> 6, lane = tid & 63;
    int m = lane & 15, g = lane >> 4;
    int rb = blockIdx.x >> 2, quarter = blockIdx.x & 3;
    int r0 = rb * 256 + w * 64;
    const v4f C2 = {2.f, 2.f, 2.f, 2.f};

    v8h a[4][8];
    #pragma unroll
    for (int h = 0; h < 4; ++h) {
        const unsigned short* ap = zfh + (size_t)(r0 + h * 16 + m) * DIM + g * 8;
        #pragma unroll
        for (int c = 0; c < 8; ++c) a[h][c] = *(const v8h*)(ap + c * 32);
    }
    asm volatile("" ::: "memory");   // pin a-loads before DMA issue order

    const char* cb_base = (const char*)cbh + ((size_t)quarter << 20);
    int wq = 4 * w;

    int roff[8];
    #pragma unroll
    for (int c = 0; c < 8; ++c)
        roff[c] = m * 512 + swz(4 * c + g, m) * 16;

    #pragma unroll
    for (int tt = 0; tt < 3; ++tt) {
        const char* gsrc = cb_base + (size_t)tt * BUF_B + wq * 1024 + lane * 16;
        char* lb = lds + (tt & 3) * BUF_B + wq * 1024;
        #pragma unroll
        for (int i = 0; i < 4; ++i) dma16(gsrc + i * 1024, lb + i * 1024);
    }

    uint top1[16], top2[16];
    #pragma unroll
    for (int i = 0; i < 16; ++i) { top1[i] = 0u; top2[i] = 0u; }

    for (int t = 0; t < NT; ++t) {
        if (t < NT - 2) asm volatile("s_waitcnt vmcnt(8)" ::: "memory");
        else            asm volatile("s_waitcnt vmcnt(0)" ::: "memory");
        __builtin_amdgcn_s_barrier();    // all waves' tile-t chunks visible
        if (t + 3 < NT) {
            const char* gsrc = cb_base + (size_t)(t + 3) * BUF_B + wq * 1024 + lane * 16;
            char* lb = lds + ((t + 3) & 3) * BUF_B + wq * 1024;
            #pragma unroll
            for (int i = 0; i < 4; ++i) dma16(gsrc + i * 1024, lb + i * 1024);
        }
        const char* cbuf = lds + (t & 3) * BUF_B;
        v4f acc[2][4];
        __builtin_amdgcn_s_setprio(1);
        #pragma unroll
        for (int s2 = 0; s2 < 2; ++s2) {
            #pragma unroll
            for (int c = 0; c < 8; ++c) {
                v8h b = *(const v8h*)(cbuf + s2 * 8192 + roff[c]);
                #pragma unroll
                for (int h = 0; h < 4; ++h) {
                    v4f cin = (c == 0) ? C2 : acc[s2][h];   // C=const: no init movs
                    acc[s2][h] = __builtin_amdgcn_mfma_f32_16x16x32_f16(a[h][c], b, cin, 0, 0, 0);
                }
            }
        }
        __builtin_amdgcn_s_setprio(0);
        uint gt0 = (uint)(quarter * 128 + 2 * t);
        uint gt1 = gt0 + 1u;
        #pragma unroll
        for (int i = 0; i < 16; ++i) {
            float s0 = acc[0][i >> 2][i & 3];           // in [1,3]: bits sortable
            float s1 = acc[1][i >> 2][i & 3];
            uint k0 = (__float_as_uint(s0) & 0xFFFFFE00u) | gt0;
            uint k1 = (__float_as_uint(s1) & 0xFFFFFE00u) | gt1;
            uint old1 = top1[i];
            top1[i] = umax3(old1, k0, k1);
            top2[i] = umax2(top2[i], umed3(old1, k0, k1));
        }
    }

    #pragma unroll
    for (int i = 0; i < 16; ++i) {
        int h = i >> 2, q = i & 3;
        int row = r0 + h * 16 + g * 4 + q;
        uint2 v2; v2.x = top1[i]; v2.y = top2[i];
        *(uint2*)(cand + (size_t)row * 128 + (quarter * 16 + m) * 2) = v2;
    }
}

// One wave per row. Prune 128 candidates at margin 0.008 (worst-case fp16 key
// skew ~0.0032), compact survivors via ballot-prefix into wave-private LDS.
// Speculative prefetch: the argmax-key lane's code is known right after the
// kmax reduce; ns==1 => spec IS the exact argmin. Loss folded in FENCE-FREE:
// per-block f64 atomicAdd into 64 slots; asm data-dependency on the returned
// value orders loss-add before count-add; last block (count==8192) reads
// slots via atomicAdd(+0.0) at the coherence point. No __threadfence.
__global__ __launch_bounds__(256) void rescore_kernel(
        const float* __restrict__ x, const float* __restrict__ cb,
        const uint* __restrict__ cand, float* __restrict__ out,
        float* __restrict__ out_idx, float* __restrict__ loss_out,
        double* __restrict__ partial, uint* __restrict__ count) {
    __shared__ int s_surv[4][128];
    __shared__ double dsm[4];
    __shared__ int is_last;
    int w = threadIdx.x >> 6, lane = threadIdx.x & 63;
    int r = blockIdx.x * 4 + w;
    // Issue both independent HBM loads back-to-back before any reduction.
    float4 xv = *(const float4*)(x + (size_t)r * DIM + lane * 4);
    uint2 kk = *(const uint2*)(cand + (size_t)r * 128 + lane * 2);

    float ss = xv.x * xv.x + xv.y * xv.y + xv.z * xv.z + xv.w * xv.w;
    #pragma unroll
    for (int o = 32; o; o >>= 1) ss += __shfl_xor(ss, o);
    float rinv = 1.0f / fmaxf(sqrtf(ss), 1e-12f);
    float4 z4; z4.x = xv.x * rinv; z4.y = xv.y * rinv; z4.z = xv.z * rinv; z4.w = xv.w * rinv;

    float kf0 = __uint_as_float(kk.x & 0xFFFFFE00u);
    float kf1 = __uint_as_float(kk.y & 0xFFFFFE00u);
    int code0 = (int)(kk.x & 0x1FFu) * 16 + (lane & 15);
    int code1 = (int)(kk.y & 0x1FFu) * 16 + (lane & 15);
    float mykey = fmaxf(kf0, kf1);
    int mycode = (kf0 >= kf1) ? code0 : code1;
    float kmax = mykey;
    #pragma unroll
    for (int o = 32; o; o >>= 1) kmax = fmaxf(kmax, __shfl_xor(kmax, o));
    // Speculative winner: first lane holding the max key. Unique when ns==1.
    ull mm = __ballot(mykey == kmax);
    int spec = __shfl(mycode, (int)__builtin_ctzll(mm));
    float4 cspec = *(const float4*)(cb + (size_t)spec * DIM + lane * 4);

    float thr = kmax - 0.008f;
    bool p0 = kf0 >= thr, p1 = kf1 >= thr;
    ull m0 = __ballot(p0), m1 = __ballot(p1);
    ull lt = (1ull << lane) - 1ull;
    int ns0 = __popcll(m0);
    int ns = ns0 + __popcll(m1);
    if (p0) s_surv[w][__popcll(m0 & lt)] = code0;
    if (p1) s_surv[w][ns0 + __popcll(m1 & lt)] = code1;
    // wave-private LDS: same-wave DS ops execute in order; no barrier needed.

    int bestj;
    if (ns == 1) {
        // Unique within-margin survivor = the kmax key's owner = spec.
        // Margin covers worst-case fp16 skew => every possible winner
        // survives; ties are never pruned. Exact.
        bestj = spec;
    } else {
        float d1 = 3.0e38f; int jj = 0x7fffffff;
        int nsl = ns < 64 ? ns : 64;
        for (int s = 0; s < nsl; ++s) {
            int j = s_surv[w][s];
            float4 c4 = *(const float4*)(cb + (size_t)j * DIM + lane * 4);
            float d = c4.x * (c4.x - 2.f * z4.x) + c4.y * (c4.y - 2.f * z4.y)
                    + c4.z * (c4.z - 2.f * z4.z) + c4.w * (c4.w - 2.f * z4.w);
            #pragma unroll
            for (int o = 32; o; o >>= 1) d += __shfl_xor(d, o);
            if (lane == s) { d1 = d; jj = j; }
        }
        if (ns > 64) {   // effectively never for this data; correctness fallback
            float d2 = 3.0e38f; int jj2 = 0x7fffffff;
            for (int s = 64; s < ns; ++s) {
                int j = s_surv[w][s];
                float4 c4 = *(const float4*)(cb + (size_t)j * DIM + lane * 4);
                float d = c4.x * (c4.x - 2.f * z4.x) + c4.y * (c4.y - 2.f * z4.y)
                        + c4.z * (c4.z - 2.f * z4.z) + c4.w * (c4.w - 2.f * z4.w);
                #pragma unroll
                for (int o = 32; o; o >>= 1) d += __shfl_xor(d, o);
                if (lane == s - 64) { d2 = d; jj2 = j; }
            }
            if (d2 < d1 || (d2 == d1 && jj2 < jj)) { d1 = d2; jj = jj2; }
        }
        float dmin = d1;
        #pragma unroll
        for (int o = 32; o; o >>= 1) dmin = fminf(dmin, __shfl_xor(dmin, o));
        ull nearm = __ballot(d1 <= dmin + 2e-4f);
        if (__popcll(nearm) == 1) {
            bestj = __shfl(jj, (int)__builtin_ctzll(nearm));   // provably exact
        } else {
            double bestd = 1e300; bestj = 0x7fffffff;
            while (nearm) {
                int b = (int)__builtin_ctzll(nearm); nearm &= nearm - 1;
                int jc = __shfl(jj, b);
                float4 c4 = *(const float4*)(cb + (size_t)jc * DIM + lane * 4);
                double p = (double)c4.x * ((double)c4.x - 2.0 * (double)z4.x)
                         + (double)c4.y * ((double)c4.y - 2.0 * (double)z4.y)
                         + (double)c4.z * ((double)c4.z - 2.0 * (double)z4.z)
                         + (double)c4.w * ((double)c4.w - 2.0 * (double)z4.w);
                #pragma unroll
                for (int o = 32; o; o >>= 1) p += __shfl_xor(p, o);
                if (p < bestd || (p == bestd && jc < bestj)) { bestd = p; bestj = jc; }
            }
        }
    }
    float4 c4;
    if (bestj == spec) c4 = cspec;    // common path: already in registers
    else c4 = *(const float4*)(cb + (size_t)bestj * DIM + lane * 4);
    *(float4*)(out + (size_t)r * DIM + lane * 4) = c4;
    double dx = (double)c4.x - (double)z4.x, dy = (double)c4.y - (double)z4.y;
    double dz = (double)c4.z - (double)z4.z, dw = (double)c4.w - (double)z4.w;
    double lp = dx * dx + dy * dy + dz * dz + dw * dw;
    #pragma unroll
    for (int o = 32; o; o >>= 1) lp += __shfl_xor(lp, o);
    if (lane == 0) { out_idx[r] = (float)bestj; dsm[w] = lp; }

    // ---- fence-free loss fold ----
    __syncthreads();
    if (threadIdx.x == 0) {
        double bsum = (dsm[0] + dsm[1]) + (dsm[2] + dsm[3]);
        // Relaxed device-scope atomic at the coherence point (no cache ops).
        double oldl = atomicAdd(&partial[blockIdx.x & 63], bsum);
        // Data dependency: wave must receive oldl (loss-add complete at the
        // coherence point) before the count-add below can issue.
        asm volatile("" :: "v"(oldl));
        uint oldc = atomicAdd(count, 1u);
        is_last = (oldc == (uint)(M_ROWS / 4 - 1));
    }
    __syncthreads();
    if (is_last && threadIdx.x < 64) {
        // All 8192 loss-adds are complete (each ordered before its count-add).
        // Atomic read at the same coherence point; no acquire fence needed.
        double p = atomicAdd(&partial[threadIdx.x], 0.0);
        #pragma unroll
        for (int o = 32; o; o >>= 1) p += __shfl_xor(p, o);
        if (threadIdx.x == 0)
            loss_out[0] = (float)(p * (1.25 / (double)(M_ROWS * DIM)));  // (BETA+1)*mean
    }
}

extern "C" void kernel_launch(void* const* d_in, const int* in_sizes, int n_in,
                              void* d_out, int out_size, void* d_ws, size_t ws_size,
                              hipStream_t stream) {
    const float* x   = (const float*)d_in[0];   // 32*1024*256
    const float* emb = (const float*)d_in[1];   // 8192*256
    float* out = (float*)d_out;
    char* ws = (char*)d_ws;

    float*          cb      = (float*)(ws);                          // 8 MB
    unsigned short* cbh     = (unsigned short*)(ws + (8u  << 20));   // 4 MB (swizzled fp16 image)
    unsigned short* zfh     = (unsigned short*)(ws + (12u << 20));   // 16 MB
    uint*           cand    = (uint*)(ws + (28u << 20));             // 16 MB
    double*         partial = (double*)(ws + (44u << 20));           // 512 B (64 slots)
    uint*           count   = (uint*)(ws + (44u << 20) + 1024);      // 4 B

    normalize_kernel<<<(N_CODES + M_ROWS) / 4, 256, 0, stream>>>(emb, x, cb, cbh, zfh,
                                                                 partial, count);
    scan_kernel<<<512, 256, 0, stream>>>(zfh, cbh, cand);
    rescore_kernel<<<M_ROWS / 4, 256, 0, stream>>>(x, cb, cand,
                                                   out,
                                                   out + ((size_t)M_ROWS * DIM + 1),
                                                   out + (size_t)M_ROWS * DIM,
                                                   partial, count);
}